// Round 13
// baseline (755.025 us; speedup 1.0000x reference)
//
#include <hip/hip_runtime.h>
#include <hip/hip_bf16.h>

#define HIDF 128
#define OUTF 64
#define BK_SHIFT 7   // 128 nodes per CSR bucket

typedef __attribute__((ext_vector_type(8))) short bf16x8;
typedef __attribute__((ext_vector_type(4))) float f32x4;

__device__ __forceinline__ float us2f(unsigned u_lo16) {
    return __uint_as_float(u_lo16 << 16);
}
__device__ __forceinline__ float hi2f(unsigned u) {
    return __uint_as_float(u & 0xffff0000u);
}
__device__ __forceinline__ unsigned short f2us(float f) {
    __hip_bfloat16 h = __float2bfloat16(f);
    return *reinterpret_cast<unsigned short*>(&h);
}
__device__ __forceinline__ unsigned pack2(float a, float b) {
    return (unsigned)f2us(a) | ((unsigned)f2us(b) << 16);
}

// ---------------- bucket histogram / scan ----------------
__global__ __launch_bounds__(256) void bhist_zero(int* __restrict__ bs, int total) {
    int i = blockIdx.x * 256 + threadIdx.x;
    if (i < total) bs[i] = 0;
}

__global__ __launch_bounds__(256) void bhist_count(const int* __restrict__ ei,
                                                   int* __restrict__ bs, int E) {
    int e = blockIdx.x * 256 + threadIdx.x;
    if (e < E) atomicAdd(&bs[(ei[E + e] >> BK_SHIFT) * 16], 1);
}

// single block: exclusive scan of NBK bucket sizes -> BSTART, init BCUR
__global__ __launch_bounds__(1024) void bscan(const int* __restrict__ bs,
                                              int* __restrict__ bstart,
                                              int* __restrict__ bcur, int NBK, int E) {
    __shared__ int ps[1024];
    const int t = threadIdx.x;
    ps[t] = (t < NBK) ? bs[t * 16] : 0;
    __syncthreads();
    for (int off = 1; off < 1024; off <<= 1) {
        int v = ps[t];
        int u = (t >= off) ? ps[t - off] : 0;
        __syncthreads();
        ps[t] = v + u;
        __syncthreads();
    }
    int ex = (t == 0) ? 0 : ps[t - 1];
    if (t < NBK) { bstart[t] = ex; bcur[t * 64] = ex; }
    if (t == 0) bstart[NBK] = E;
}

// pass 1: scatter packed (src<<7 | dst&127) into bucket-grouped regions of EDG
__global__ __launch_bounds__(256) void bucket_scatter(const int* __restrict__ ei,
                                                      int* __restrict__ bcur,
                                                      unsigned* __restrict__ edg, int E) {
    int e = blockIdx.x * 256 + threadIdx.x;
    if (e >= E) return;
    int src = ei[e];
    int dst = ei[E + e];
    int pos = atomicAdd(&bcur[(dst >> BK_SHIFT) * 64], 1);
    edg[pos] = ((unsigned)src << BK_SHIFT) | (unsigned)(dst & ((1 << BK_SHIFT) - 1));
}

// pass 2: one block per bucket — LDS histogram + scan, write rend/dinv/csr_src
__global__ __launch_bounds__(256) void csr_build(const unsigned* __restrict__ edg,
                                                 const int* __restrict__ bstart,
                                                 int* __restrict__ rend,
                                                 int* __restrict__ csr_src,
                                                 float* __restrict__ dinv, int N) {
    const int b = blockIdx.x;
    const int lo = bstart[b], hi = bstart[b + 1];
    const int base = b << BK_SHIFT;
    __shared__ int hist[128], curs[128], ps[128];
    if (threadIdx.x < 128) hist[threadIdx.x] = 0;
    __syncthreads();
    for (int p = lo + threadIdx.x; p < hi; p += 256)
        atomicAdd(&hist[edg[p] & 127], 1);
    __syncthreads();
    if (threadIdx.x < 128) ps[threadIdx.x] = hist[threadIdx.x];
    __syncthreads();
    for (int off = 1; off < 128; off <<= 1) {
        int v = 0;
        if (threadIdx.x < 128) {
            v = ps[threadIdx.x];
            if (threadIdx.x >= off) v += ps[threadIdx.x - off];
        }
        __syncthreads();
        if (threadIdx.x < 128) ps[threadIdx.x] = v;
        __syncthreads();
    }
    if (threadIdx.x < 128) {
        int n = base + threadIdx.x;
        if (n < N) {
            int inc = ps[threadIdx.x];
            int d   = hist[threadIdx.x];
            rend[n] = lo + inc;
            curs[threadIdx.x] = lo + inc - d;
            dinv[n] = rsqrtf((float)d + 1.f);
        }
    }
    __syncthreads();
    for (int p = lo + threadIdx.x; p < hi; p += 256) {
        unsigned u = edg[p];
        int pos = atomicAdd(&curs[u & 127], 1);
        csr_src[pos] = (int)(u >> BK_SHIFT);
    }
}

// ---------------- convert: TB[n,:] = bf16( x[n,:] * dinv[n] ) ----------------
__global__ __launch_bounds__(256) void cvt_scale(const float* __restrict__ X,
                                                 const float* __restrict__ dinv,
                                                 unsigned short* __restrict__ TB, int N) {
    int g = blockIdx.x * 256 + threadIdx.x;
    if (g >= N * 32) return;
    int n = g >> 5;
    float dv = dinv[n];
    float4 v = ((const float4*)X)[g];
    ushort4 o;
    o.x = f2us(v.x * dv); o.y = f2us(v.y * dv);
    o.z = f2us(v.z * dv); o.w = f2us(v.w * dv);
    ((ushort4*)TB)[g] = o;
}

// ---------------- convert 6 weight matrices f32 [k][n] -> bf16 transposed [n][k] ----------------
__global__ __launch_bounds__(256) void cvt_w(const float* __restrict__ Wa0,
                                             const float* __restrict__ Wa1,
                                             const float* __restrict__ Wa2,
                                             const float* __restrict__ Wa3,
                                             const float* __restrict__ Wa4,
                                             const float* __restrict__ Wa5,
                                             unsigned short* __restrict__ WTB) {
    int t = blockIdx.x * 256 + threadIdx.x;
    if (t >= 6 * 16384) return;
    int m = t >> 14, local = t & 16383;
    int n = local >> 7, k = local & 127;
    const float* src = (m == 0) ? Wa0 : (m == 1) ? Wa1 : (m == 2) ? Wa2
                     : (m == 3) ? Wa3 : (m == 4) ? Wa4 : Wa5;
    WTB[t] = f2us(src[k * 128 + n]);
}

// ---------------- single CSR aggregation, paired-edge uint2 gather, 16/8/2/1 unroll ----------------
__global__ __launch_bounds__(256) void agg_b2(const unsigned short* __restrict__ TB,
                                              const float* __restrict__ dinv,
                                              const int* __restrict__ csr_src,
                                              const int* __restrict__ rend,
                                              unsigned* __restrict__ O, int N) {
    const int n = (blockIdx.x * 256 + threadIdx.x) >> 6;
    const int l = threadIdx.x & 63;
    if (n >= N) return;
    const int half = l >> 5;
    const int sl   = l & 31;
    const int start = (n == 0) ? 0 : rend[n - 1];
    const int end   = rend[n];
    const uint2* Tv = (const uint2*)TB;   // row = 32 uint2 (256 B)

    float a0 = 0.f, a1 = 0.f, a2 = 0.f, a3 = 0.f;
    int e = start;
    for (; e + 16 <= end; e += 16) {      // 8 loads/lane in flight
        int sA = csr_src[e +  0 + half], sB = csr_src[e +  2 + half];
        int sC = csr_src[e +  4 + half], sD = csr_src[e +  6 + half];
        int sE = csr_src[e +  8 + half], sF = csr_src[e + 10 + half];
        int sG = csr_src[e + 12 + half], sH = csr_src[e + 14 + half];
        uint2 vA = Tv[(size_t)sA * 32 + sl];
        uint2 vB = Tv[(size_t)sB * 32 + sl];
        uint2 vC = Tv[(size_t)sC * 32 + sl];
        uint2 vD = Tv[(size_t)sD * 32 + sl];
        uint2 vE = Tv[(size_t)sE * 32 + sl];
        uint2 vF = Tv[(size_t)sF * 32 + sl];
        uint2 vG = Tv[(size_t)sG * 32 + sl];
        uint2 vH = Tv[(size_t)sH * 32 + sl];
        a0 += us2f(vA.x & 0xffffu); a1 += hi2f(vA.x); a2 += us2f(vA.y & 0xffffu); a3 += hi2f(vA.y);
        a0 += us2f(vB.x & 0xffffu); a1 += hi2f(vB.x); a2 += us2f(vB.y & 0xffffu); a3 += hi2f(vB.y);
        a0 += us2f(vC.x & 0xffffu); a1 += hi2f(vC.x); a2 += us2f(vC.y & 0xffffu); a3 += hi2f(vC.y);
        a0 += us2f(vD.x & 0xffffu); a1 += hi2f(vD.x); a2 += us2f(vD.y & 0xffffu); a3 += hi2f(vD.y);
        a0 += us2f(vE.x & 0xffffu); a1 += hi2f(vE.x); a2 += us2f(vE.y & 0xffffu); a3 += hi2f(vE.y);
        a0 += us2f(vF.x & 0xffffu); a1 += hi2f(vF.x); a2 += us2f(vF.y & 0xffffu); a3 += hi2f(vF.y);
        a0 += us2f(vG.x & 0xffffu); a1 += hi2f(vG.x); a2 += us2f(vG.y & 0xffffu); a3 += hi2f(vG.y);
        a0 += us2f(vH.x & 0xffffu); a1 += hi2f(vH.x); a2 += us2f(vH.y & 0xffffu); a3 += hi2f(vH.y);
    }
    if (e + 8 <= end) {
        int sA = csr_src[e + 0 + half], sB = csr_src[e + 2 + half];
        int sC = csr_src[e + 4 + half], sD = csr_src[e + 6 + half];
        uint2 vA = Tv[(size_t)sA * 32 + sl];
        uint2 vB = Tv[(size_t)sB * 32 + sl];
        uint2 vC = Tv[(size_t)sC * 32 + sl];
        uint2 vD = Tv[(size_t)sD * 32 + sl];
        a0 += us2f(vA.x & 0xffffu); a1 += hi2f(vA.x); a2 += us2f(vA.y & 0xffffu); a3 += hi2f(vA.y);
        a0 += us2f(vB.x & 0xffffu); a1 += hi2f(vB.x); a2 += us2f(vB.y & 0xffffu); a3 += hi2f(vB.y);
        a0 += us2f(vC.x & 0xffffu); a1 += hi2f(vC.x); a2 += us2f(vC.y & 0xffffu); a3 += hi2f(vC.y);
        a0 += us2f(vD.x & 0xffffu); a1 += hi2f(vD.x); a2 += us2f(vD.y & 0xffffu); a3 += hi2f(vD.y);
        e += 8;
    }
    for (; e + 2 <= end; e += 2) {
        int s = csr_src[e + half];
        uint2 v = Tv[(size_t)s * 32 + sl];
        a0 += us2f(v.x & 0xffffu); a1 += hi2f(v.x); a2 += us2f(v.y & 0xffffu); a3 += hi2f(v.y);
    }
    if (e < end && half == 0) {
        int s = csr_src[e];
        uint2 v = Tv[(size_t)s * 32 + sl];
        a0 += us2f(v.x & 0xffffu); a1 += hi2f(v.x); a2 += us2f(v.y & 0xffffu); a3 += hi2f(v.y);
    }
    if (half == 0) {                      // self-loop
        uint2 v = Tv[(size_t)n * 32 + sl];
        a0 += us2f(v.x & 0xffffu); a1 += hi2f(v.x); a2 += us2f(v.y & 0xffffu); a3 += hi2f(v.y);
    }
    a0 += __shfl_xor(a0, 32); a1 += __shfl_xor(a1, 32);
    a2 += __shfl_xor(a2, 32); a3 += __shfl_xor(a3, 32);
    if (half == 0) {
        const float dv = dinv[n];
        uint2 o;
        o.x = pack2(a0 * dv, a1 * dv);
        o.y = pack2(a2 * dv, a3 * dv);
        ((uint2*)O)[(size_t)n * 32 + sl] = o;
    }
}

// ---------------- dual CSR aggregation: 512B contiguous load per edge, 8/1 unroll ----------------
__global__ __launch_bounds__(256) void agg_dual2(const unsigned short* __restrict__ TB23,
                                                 const float* __restrict__ dinv,
                                                 const int* __restrict__ csr_src,
                                                 const int* __restrict__ rend,
                                                 unsigned* __restrict__ OA,
                                                 unsigned* __restrict__ OB, int N) {
    const int n = (blockIdx.x * 256 + threadIdx.x) >> 6;
    const int l = threadIdx.x & 63;
    if (n >= N) return;
    const int start = (n == 0) ? 0 : rend[n - 1];
    const int end   = rend[n];
    const uint2* Tv = (const uint2*)TB23;  // node chunk = 64 uint2: slots 0-31 g2, 32-63 g3

    float a0 = 0.f, a1 = 0.f, a2 = 0.f, a3 = 0.f;
    int e = start;
    for (; e + 8 <= end; e += 8) {        // 8 gathers in flight
        int s0 = csr_src[e + 0], s1 = csr_src[e + 1], s2 = csr_src[e + 2], s3 = csr_src[e + 3];
        int s4 = csr_src[e + 4], s5 = csr_src[e + 5], s6 = csr_src[e + 6], s7 = csr_src[e + 7];
        uint2 v0 = Tv[(size_t)s0 * 64 + l];
        uint2 v1 = Tv[(size_t)s1 * 64 + l];
        uint2 v2 = Tv[(size_t)s2 * 64 + l];
        uint2 v3 = Tv[(size_t)s3 * 64 + l];
        uint2 v4 = Tv[(size_t)s4 * 64 + l];
        uint2 v5 = Tv[(size_t)s5 * 64 + l];
        uint2 v6 = Tv[(size_t)s6 * 64 + l];
        uint2 v7 = Tv[(size_t)s7 * 64 + l];
        a0 += us2f(v0.x & 0xffffu); a1 += hi2f(v0.x); a2 += us2f(v0.y & 0xffffu); a3 += hi2f(v0.y);
        a0 += us2f(v1.x & 0xffffu); a1 += hi2f(v1.x); a2 += us2f(v1.y & 0xffffu); a3 += hi2f(v1.y);
        a0 += us2f(v2.x & 0xffffu); a1 += hi2f(v2.x); a2 += us2f(v2.y & 0xffffu); a3 += hi2f(v2.y);
        a0 += us2f(v3.x & 0xffffu); a1 += hi2f(v3.x); a2 += us2f(v3.y & 0xffffu); a3 += hi2f(v3.y);
        a0 += us2f(v4.x & 0xffffu); a1 += hi2f(v4.x); a2 += us2f(v4.y & 0xffffu); a3 += hi2f(v4.y);
        a0 += us2f(v5.x & 0xffffu); a1 += hi2f(v5.x); a2 += us2f(v5.y & 0xffffu); a3 += hi2f(v5.y);
        a0 += us2f(v6.x & 0xffffu); a1 += hi2f(v6.x); a2 += us2f(v6.y & 0xffffu); a3 += hi2f(v6.y);
        a0 += us2f(v7.x & 0xffffu); a1 += hi2f(v7.x); a2 += us2f(v7.y & 0xffffu); a3 += hi2f(v7.y);
    }
    for (; e < end; ++e) {
        int s = csr_src[e];
        uint2 v = Tv[(size_t)s * 64 + l];
        a0 += us2f(v.x & 0xffffu); a1 += hi2f(v.x); a2 += us2f(v.y & 0xffffu); a3 += hi2f(v.y);
    }
    {   // self-loop
        uint2 v = Tv[(size_t)n * 64 + l];
        a0 += us2f(v.x & 0xffffu); a1 += hi2f(v.x); a2 += us2f(v.y & 0xffffu); a3 += hi2f(v.y);
    }
    const float dv = dinv[n];
    uint2 o;
    o.x = pack2(a0 * dv, a1 * dv);
    o.y = pack2(a2 * dv, a3 * dv);
    if (l < 32) ((uint2*)OA)[(size_t)n * 32 + l] = o;
    else        ((uint2*)OB)[(size_t)n * 32 + (l - 32)] = o;
}

// ---------------- MFMA GEMM: T = X @ W + b (bf16 in via LDS; out bf16 or f32) ----------------
#define OM_F32 0
#define OM_BF16 1
#define OM_BF16_SR 2
template <int OMODE, int OSTRIDE>
__global__ __launch_bounds__(256) void gemm_mfma(const unsigned short* __restrict__ Xb,
                                                 const unsigned short* __restrict__ WT,
                                                 const float* __restrict__ bias,
                                                 const float* __restrict__ dinv,
                                                 void* __restrict__ T, int N) {
    __shared__ unsigned short Xs[64 * 128];   // 16 KB
    __shared__ unsigned short Ws[128 * 128];  // 32 KB
    const int tid = threadIdx.x;
    const int nb = blockIdx.x * 64;

    for (int c = tid; c < 2048; c += 256) {
        int n = c >> 4, kc = c & 15;
        ((uint4*)Ws)[(n << 4) | (kc ^ (n & 7))] = ((const uint4*)WT)[c];
    }
    for (int c = tid; c < 1024; c += 256) {
        int nl = c >> 4, kc = c & 15;
        int n = nb + nl;
        uint4 v = make_uint4(0u, 0u, 0u, 0u);
        if (n < N) v = ((const uint4*)(Xb + (size_t)n * HIDF))[kc];
        ((uint4*)Xs)[(nl << 4) | (kc ^ (nl & 7))] = v;
    }
    __syncthreads();

    const int wv   = tid >> 6;
    const int l    = tid & 63;
    const int row  = l & 15;
    const int kgrp = l >> 4;

    bf16x8 afr[4];
    #pragma unroll
    for (int kk = 0; kk < 4; ++kk) {
        int nl = 16 * wv + row;
        int kc = kk * 4 + kgrp;
        afr[kk] = *(const bf16x8*)(Xs + nl * 128 + ((kc ^ (nl & 7)) << 3));
    }

    f32x4 acc[8];
    #pragma unroll
    for (int nt = 0; nt < 8; ++nt) {
        float b = bias[nt * 16 + row];
        acc[nt] = (f32x4){b, b, b, b};
    }

    #pragma unroll
    for (int nt = 0; nt < 8; ++nt) {
        int col = nt * 16 + row;
        #pragma unroll
        for (int kk = 0; kk < 4; ++kk) {
            int kc = kk * 4 + kgrp;
            bf16x8 bfr = *(const bf16x8*)(Ws + col * 128 + ((kc ^ (col & 7)) << 3));
            acc[nt] = __builtin_amdgcn_mfma_f32_16x16x32_bf16(afr[kk], bfr, acc[nt], 0, 0, 0);
        }
    }

    float dv[4];
    if (OMODE == OM_BF16_SR) {
        #pragma unroll
        for (int r = 0; r < 4; ++r) {
            int grow = nb + 16 * wv + kgrp * 4 + r;
            dv[r] = (grow < N) ? dinv[grow] : 0.f;
        }
    }
    #pragma unroll
    for (int nt = 0; nt < 8; ++nt) {
        int gcol = nt * 16 + row;
        #pragma unroll
        for (int r = 0; r < 4; ++r) {
            int grow = nb + 16 * wv + kgrp * 4 + r;
            if (grow < N) {
                float v = acc[nt][r];
                if (OMODE == OM_BF16_SR) v = fmaxf(v, 0.f) * dv[r];
                if (OMODE == OM_F32) {
                    ((float*)T)[(size_t)grow * OSTRIDE + gcol] = v;
                } else {
                    ((unsigned short*)T)[(size_t)grow * OSTRIDE + gcol] = f2us(v);
                }
            }
        }
    }
}

// ---------------- meta: lane owns cols {2l, 2l+1}; vectorized loads ----------------
__global__ __launch_bounds__(256) void meta_kernel(const float* __restrict__ H1,
                                                   const unsigned* __restrict__ H2B,
                                                   const unsigned* __restrict__ H3B,
                                                   const float* __restrict__ Wa,
                                                   const float* __restrict__ ba,
                                                   const float* __restrict__ Wf,
                                                   const float* __restrict__ bfb,
                                                   float* __restrict__ out, int N) {
    __shared__ float WfS[HIDF * OUTF];  // 32 KB
    __shared__ float WaS[HIDF];
    __shared__ float hm[4][HIDF];
    const int tid = threadIdx.x;
    for (int i = tid; i < HIDF * OUTF; i += 256) WfS[i] = Wf[i];
    if (tid < HIDF) WaS[tid] = Wa[tid];
    __syncthreads();
    const float bav = ba[0];
    const int w = tid >> 6;
    const int l = tid & 63;
    const float bfv = bfb[l];
    const int iters = (N + 3) >> 2;

    for (int it = blockIdx.x; it < iters; it += gridDim.x) {
        const int n = it * 4 + w;
        __syncthreads();
        if (n < N) {
            float2   p1 = ((const float2*)(H1 + (size_t)n * HIDF))[l];
            unsigned u2 = H2B[(size_t)n * 64 + l];
            unsigned u3 = H3B[(size_t)n * 64 + l];
            float h1a = fmaxf(p1.x, 0.f),               h1b = fmaxf(p1.y, 0.f);
            float h2a = fmaxf(us2f(u2 & 0xffffu), 0.f), h2b = fmaxf(hi2f(u2), 0.f);
            float h3a = fmaxf(us2f(u3 & 0xffffu), 0.f), h3b = fmaxf(hi2f(u3), 0.f);
            float wa0 = WaS[2 * l], wa1 = WaS[2 * l + 1];
            float s1 = h1a * wa0 + h1b * wa1;
            float s2 = h2a * wa0 + h2b * wa1;
            float s3 = h3a * wa0 + h3b * wa1;
            #pragma unroll
            for (int off = 32; off; off >>= 1) {
                s1 += __shfl_xor(s1, off);
                s2 += __shfl_xor(s2, off);
                s3 += __shfl_xor(s3, off);
            }
            s1 += bav; s2 += bav; s3 += bav;
            float m  = fmaxf(s1, fmaxf(s2, s3));
            float e1 = expf(s1 - m), e2 = expf(s2 - m), e3 = expf(s3 - m);
            float inv = 1.f / (e1 + e2 + e3);
            float w1 = e1 * inv, w2 = e2 * inv, w3 = e3 * inv;
            hm[w][2 * l]     = w1 * h1a + w2 * h2a + w3 * h3a + h1a;
            hm[w][2 * l + 1] = w1 * h1b + w2 * h2b + w3 * h3b + h1b;
        }
        __syncthreads();
        if (n < N) {
            float acc = bfv;
            #pragma unroll
            for (int k = 0; k < HIDF; ++k) acc = fmaf(hm[w][k], WfS[k * OUTF + l], acc);
            out[(size_t)n * OUTF + l] = acc;
        }
    }
}

// ---------------- launch ----------------
extern "C" void kernel_launch(void* const* d_in, const int* in_sizes, int n_in,
                              void* d_out, int out_size, void* d_ws, size_t ws_size,
                              hipStream_t stream) {
    const float* x   = (const float*)d_in[0];
    const int*   ei  = (const int*)d_in[1];
    const float *W1  = (const float*)d_in[2],  *b1  = (const float*)d_in[3];
    const float *W21 = (const float*)d_in[4],  *b21 = (const float*)d_in[5];
    const float *W22 = (const float*)d_in[6],  *b22 = (const float*)d_in[7];
    const float *W31 = (const float*)d_in[8],  *b31 = (const float*)d_in[9];
    const float *W32 = (const float*)d_in[10], *b32 = (const float*)d_in[11];
    const float *W33 = (const float*)d_in[12], *b33 = (const float*)d_in[13];
    const float *Wa  = (const float*)d_in[14], *ba  = (const float*)d_in[15];
    const float *Wf  = (const float*)d_in[16], *bfb = (const float*)d_in[17];

    const int N = in_sizes[0] / HIDF;
    const int E = in_sizes[1] / 2;
    const int NBK = (N + 127) >> BK_SHIFT;

    // workspace: ints | DINV | TB23 (later aliased by H1F f32) | PXB | AGA | AGB | H2B | WTB
    int*      REND    = (int*)d_ws;                        // N  (row ends)
    int*      CSR_SRC = REND + N;                          // E
    unsigned* EDG     = (unsigned*)(CSR_SRC + E);          // E packed records
    int*      BCUR    = (int*)(EDG + E);                   // 1024*64 (padded)
    int*      BSIZE   = BCUR + 1024 * 64;                  // 1024*16 (padded)
    int*      BSTART  = BSIZE + 1024 * 16;                 // 1025
    float*    DINV    = (float*)(BSTART + 1040);           // N
    unsigned short* TB23 = (unsigned short*)(DINV + N);    // N*256 bf16 (later: H1F f32 N*128)
    unsigned* PXB  = (unsigned*)(TB23 + (size_t)N * 256);  // N*64 uints
    unsigned* AGA  = PXB + (size_t)N * 64;                 // N*64 uints
    unsigned* AGB  = AGA + (size_t)N * 64;                 // N*64 uints
    unsigned* H2B  = AGB + (size_t)N * 64;                 // N*64 uints
    unsigned short* WTB = (unsigned short*)(H2B + (size_t)N * 64);  // 6*16384 bf16

    const int gE    = (E + 255) / 256;
    const int gCVT  = (N * 32 + 255) / 256;
    const int gAGG  = (N * 64 + 255) / 256;
    const int gGEMM = (N + 63) / 64;
    const int gMETA = 2048;

    // CSR build (single-pass bucketed) + weight pre-transpose
    bhist_zero<<<(NBK * 16 + 255) / 256, 256, 0, stream>>>(BSIZE, NBK * 16);
    bhist_count<<<gE, 256, 0, stream>>>(ei, BSIZE, E);
    bscan<<<1, 1024, 0, stream>>>(BSIZE, BSTART, BCUR, NBK, E);
    bucket_scatter<<<gE, 256, 0, stream>>>(ei, BCUR, EDG, E);
    csr_build<<<NBK, 256, 0, stream>>>(EDG, BSTART, REND, CSR_SRC, DINV, N);
    cvt_w<<<384, 256, 0, stream>>>(W21, W31, W22, W32, W33, W1, WTB);

    unsigned short* TBX = TB23;   // plain [n][128] bf16 view of TB23 region

    // TBX = bf16(x*dinv); PXB = bf16( P x )
    cvt_scale<<<gCVT, 256, 0, stream>>>(x, DINV, TBX, N);
    agg_b2<<<gAGG, 256, 0, stream>>>(TBX, DINV, CSR_SRC, REND, PXB, N);

    // branch layer-1: TB23 = {g2, g3}
    gemm_mfma<OM_BF16_SR, 256><<<gGEMM, 256, 0, stream>>>((unsigned short*)PXB, WTB,         b21, DINV, TB23,       N);
    gemm_mfma<OM_BF16_SR, 256><<<gGEMM, 256, 0, stream>>>((unsigned short*)PXB, WTB + 16384, b31, DINV, TB23 + 128, N);
    // fused aggregation: AGA = P g2, AGB = P g3
    agg_dual2<<<gAGG, 256, 0, stream>>>(TB23, DINV, CSR_SRC, REND, AGA, AGB, N);

    // h2 finish: H2B = AGA@W22+b22
    gemm_mfma<OM_BF16, 128><<<gGEMM, 256, 0, stream>>>((unsigned short*)AGA, WTB + 2 * 16384, b22, DINV, H2B, N);
    // h3 second layer: TBX = relu(AGB@W32+b32)*dinv
    gemm_mfma<OM_BF16_SR, 128><<<gGEMM, 256, 0, stream>>>((unsigned short*)AGB, WTB + 3 * 16384, b32, DINV, TBX, N);
    // h3 aggregation: AGA = P TBX
    agg_b2<<<gAGG, 256, 0, stream>>>(TBX, DINV, CSR_SRC, REND, AGA, N);
    // h3 finish: H3B (=AGB) = AGA@W33+b33
    gemm_mfma<OM_BF16, 128><<<gGEMM, 256, 0, stream>>>((unsigned short*)AGA, WTB + 4 * 16384, b33, DINV, AGB, N);

    // h1: H1F (f32, aliases TB23 region; TBX dead) = PXB@W1+b1
    float* H1F = (float*)TB23;
    gemm_mfma<OM_F32, 128><<<gGEMM, 256, 0, stream>>>((unsigned short*)PXB, WTB + 5 * 16384, b1, DINV, H1F, N);

    // meta combine + final projection
    meta_kernel<<<gMETA, 256, 0, stream>>>(H1F, H2B, AGB, Wa, ba, Wf, bfb,
                                           (float*)d_out, N);
}

// Round 14
// 742.566 us; speedup vs baseline: 1.0168x; 1.0168x over previous
//
#include <hip/hip_runtime.h>
#include <hip/hip_bf16.h>

#define HIDF 128
#define OUTF 64
#define BK_SHIFT 7   // 128 nodes per CSR bucket

typedef __attribute__((ext_vector_type(8))) short bf16x8;
typedef __attribute__((ext_vector_type(4))) float f32x4;

__device__ __forceinline__ float us2f(unsigned u_lo16) {
    return __uint_as_float(u_lo16 << 16);
}
__device__ __forceinline__ float hi2f(unsigned u) {
    return __uint_as_float(u & 0xffff0000u);
}
__device__ __forceinline__ unsigned short f2us(float f) {
    __hip_bfloat16 h = __float2bfloat16(f);
    return *reinterpret_cast<unsigned short*>(&h);
}
__device__ __forceinline__ unsigned pack2(float a, float b) {
    return (unsigned)f2us(a) | ((unsigned)f2us(b) << 16);
}

// ---------------- bucket histogram / scan ----------------
__global__ __launch_bounds__(256) void bhist_zero(int* __restrict__ bs, int total) {
    int i = blockIdx.x * 256 + threadIdx.x;
    if (i < total) bs[i] = 0;
}

__global__ __launch_bounds__(256) void bhist_count(const int* __restrict__ ei,
                                                   int* __restrict__ bs, int E) {
    int e = blockIdx.x * 256 + threadIdx.x;
    if (e < E) atomicAdd(&bs[(ei[E + e] >> BK_SHIFT) * 16], 1);
}

// single block: exclusive scan of NBK bucket sizes -> BSTART, init BCUR
__global__ __launch_bounds__(1024) void bscan(const int* __restrict__ bs,
                                              int* __restrict__ bstart,
                                              int* __restrict__ bcur, int NBK, int E) {
    __shared__ int ps[1024];
    const int t = threadIdx.x;
    ps[t] = (t < NBK) ? bs[t * 16] : 0;
    __syncthreads();
    for (int off = 1; off < 1024; off <<= 1) {
        int v = ps[t];
        int u = (t >= off) ? ps[t - off] : 0;
        __syncthreads();
        ps[t] = v + u;
        __syncthreads();
    }
    int ex = (t == 0) ? 0 : ps[t - 1];
    if (t < NBK) { bstart[t] = ex; bcur[t * 64] = ex; }
    if (t == 0) bstart[NBK] = E;
}

// pass 1: scatter packed (src<<7 | dst&127) into bucket-grouped regions of EDG
__global__ __launch_bounds__(256) void bucket_scatter(const int* __restrict__ ei,
                                                      int* __restrict__ bcur,
                                                      unsigned* __restrict__ edg, int E) {
    int e = blockIdx.x * 256 + threadIdx.x;
    if (e >= E) return;
    int src = ei[e];
    int dst = ei[E + e];
    int pos = atomicAdd(&bcur[(dst >> BK_SHIFT) * 64], 1);
    edg[pos] = ((unsigned)src << BK_SHIFT) | (unsigned)(dst & ((1 << BK_SHIFT) - 1));
}

// pass 2: one block per bucket — LDS histogram + scan, write rend/dinv/csr_src
__global__ __launch_bounds__(256) void csr_build(const unsigned* __restrict__ edg,
                                                 const int* __restrict__ bstart,
                                                 int* __restrict__ rend,
                                                 int* __restrict__ csr_src,
                                                 float* __restrict__ dinv, int N) {
    const int b = blockIdx.x;
    const int lo = bstart[b], hi = bstart[b + 1];
    const int base = b << BK_SHIFT;
    __shared__ int hist[128], curs[128], ps[128];
    if (threadIdx.x < 128) hist[threadIdx.x] = 0;
    __syncthreads();
    for (int p = lo + threadIdx.x; p < hi; p += 256)
        atomicAdd(&hist[edg[p] & 127], 1);
    __syncthreads();
    if (threadIdx.x < 128) ps[threadIdx.x] = hist[threadIdx.x];
    __syncthreads();
    for (int off = 1; off < 128; off <<= 1) {
        int v = 0;
        if (threadIdx.x < 128) {
            v = ps[threadIdx.x];
            if (threadIdx.x >= off) v += ps[threadIdx.x - off];
        }
        __syncthreads();
        if (threadIdx.x < 128) ps[threadIdx.x] = v;
        __syncthreads();
    }
    if (threadIdx.x < 128) {
        int n = base + threadIdx.x;
        if (n < N) {
            int inc = ps[threadIdx.x];
            int d   = hist[threadIdx.x];
            rend[n] = lo + inc;
            curs[threadIdx.x] = lo + inc - d;
            dinv[n] = rsqrtf((float)d + 1.f);
        }
    }
    __syncthreads();
    for (int p = lo + threadIdx.x; p < hi; p += 256) {
        unsigned u = edg[p];
        int pos = atomicAdd(&curs[u & 127], 1);
        csr_src[pos] = (int)(u >> BK_SHIFT);
    }
}

// ---------------- convert: TB[n,:] = bf16( x[n,:] * dinv[n] ) ----------------
__global__ __launch_bounds__(256) void cvt_scale(const float* __restrict__ X,
                                                 const float* __restrict__ dinv,
                                                 unsigned short* __restrict__ TB, int N) {
    int g = blockIdx.x * 256 + threadIdx.x;
    if (g >= N * 32) return;
    int n = g >> 5;
    float dv = dinv[n];
    float4 v = ((const float4*)X)[g];
    ushort4 o;
    o.x = f2us(v.x * dv); o.y = f2us(v.y * dv);
    o.z = f2us(v.z * dv); o.w = f2us(v.w * dv);
    ((ushort4*)TB)[g] = o;
}

// ---------------- convert 6 weight matrices f32 [k][n] -> bf16 transposed [n][k] ----------------
__global__ __launch_bounds__(256) void cvt_w(const float* __restrict__ Wa0,
                                             const float* __restrict__ Wa1,
                                             const float* __restrict__ Wa2,
                                             const float* __restrict__ Wa3,
                                             const float* __restrict__ Wa4,
                                             const float* __restrict__ Wa5,
                                             unsigned short* __restrict__ WTB) {
    int t = blockIdx.x * 256 + threadIdx.x;
    if (t >= 6 * 16384) return;
    int m = t >> 14, local = t & 16383;
    int n = local >> 7, k = local & 127;
    const float* src = (m == 0) ? Wa0 : (m == 1) ? Wa1 : (m == 2) ? Wa2
                     : (m == 3) ? Wa3 : (m == 4) ? Wa4 : Wa5;
    WTB[t] = f2us(src[k * 128 + n]);
}

// ---------------- single CSR aggregation, paired-edge uint2 gather (round-12 depth) ----------------
__global__ __launch_bounds__(256) void agg_b2(const unsigned short* __restrict__ TB,
                                              const float* __restrict__ dinv,
                                              const int* __restrict__ csr_src,
                                              const int* __restrict__ rend,
                                              unsigned* __restrict__ O, int N) {
    const int n = (blockIdx.x * 256 + threadIdx.x) >> 6;
    const int l = threadIdx.x & 63;
    if (n >= N) return;
    const int half = l >> 5;
    const int sl   = l & 31;
    const int start = (n == 0) ? 0 : rend[n - 1];
    const int end   = rend[n];
    const uint2* Tv = (const uint2*)TB;   // row = 32 uint2 (256 B)

    float a0 = 0.f, a1 = 0.f, a2 = 0.f, a3 = 0.f;
    int e = start;
    for (; e + 8 <= end; e += 8) {        // 4 loads/lane in flight (sweet spot, r12)
        int sA = csr_src[e + 0 + half];
        int sB = csr_src[e + 2 + half];
        int sC = csr_src[e + 4 + half];
        int sD = csr_src[e + 6 + half];
        uint2 vA = Tv[(size_t)sA * 32 + sl];
        uint2 vB = Tv[(size_t)sB * 32 + sl];
        uint2 vC = Tv[(size_t)sC * 32 + sl];
        uint2 vD = Tv[(size_t)sD * 32 + sl];
        a0 += us2f(vA.x & 0xffffu); a1 += hi2f(vA.x); a2 += us2f(vA.y & 0xffffu); a3 += hi2f(vA.y);
        a0 += us2f(vB.x & 0xffffu); a1 += hi2f(vB.x); a2 += us2f(vB.y & 0xffffu); a3 += hi2f(vB.y);
        a0 += us2f(vC.x & 0xffffu); a1 += hi2f(vC.x); a2 += us2f(vC.y & 0xffffu); a3 += hi2f(vC.y);
        a0 += us2f(vD.x & 0xffffu); a1 += hi2f(vD.x); a2 += us2f(vD.y & 0xffffu); a3 += hi2f(vD.y);
    }
    for (; e + 2 <= end; e += 2) {
        int s = csr_src[e + half];
        uint2 v = Tv[(size_t)s * 32 + sl];
        a0 += us2f(v.x & 0xffffu); a1 += hi2f(v.x); a2 += us2f(v.y & 0xffffu); a3 += hi2f(v.y);
    }
    if (e < end && half == 0) {           // odd leftover edge
        int s = csr_src[e];
        uint2 v = Tv[(size_t)s * 32 + sl];
        a0 += us2f(v.x & 0xffffu); a1 += hi2f(v.x); a2 += us2f(v.y & 0xffffu); a3 += hi2f(v.y);
    }
    if (half == 0) {                      // self-loop
        uint2 v = Tv[(size_t)n * 32 + sl];
        a0 += us2f(v.x & 0xffffu); a1 += hi2f(v.x); a2 += us2f(v.y & 0xffffu); a3 += hi2f(v.y);
    }
    a0 += __shfl_xor(a0, 32); a1 += __shfl_xor(a1, 32);
    a2 += __shfl_xor(a2, 32); a3 += __shfl_xor(a3, 32);
    if (half == 0) {
        const float dv = dinv[n];
        uint2 o;
        o.x = pack2(a0 * dv, a1 * dv);
        o.y = pack2(a2 * dv, a3 * dv);
        ((uint2*)O)[(size_t)n * 32 + sl] = o;
    }
}

// ---------------- dual CSR aggregation: 512B contiguous load per edge (round-12 depth) ----------------
__global__ __launch_bounds__(256) void agg_dual2(const unsigned short* __restrict__ TB23,
                                                 const float* __restrict__ dinv,
                                                 const int* __restrict__ csr_src,
                                                 const int* __restrict__ rend,
                                                 unsigned* __restrict__ OA,
                                                 unsigned* __restrict__ OB, int N) {
    const int n = (blockIdx.x * 256 + threadIdx.x) >> 6;
    const int l = threadIdx.x & 63;
    if (n >= N) return;
    const int start = (n == 0) ? 0 : rend[n - 1];
    const int end   = rend[n];
    const uint2* Tv = (const uint2*)TB23;  // node chunk = 64 uint2: slots 0-31 g2, 32-63 g3

    float a0 = 0.f, a1 = 0.f, a2 = 0.f, a3 = 0.f;
    int e = start;
    for (; e + 4 <= end; e += 4) {         // 4 gathers in flight (sweet spot, r12)
        int s0 = csr_src[e + 0], s1 = csr_src[e + 1], s2 = csr_src[e + 2], s3 = csr_src[e + 3];
        uint2 v0 = Tv[(size_t)s0 * 64 + l];
        uint2 v1 = Tv[(size_t)s1 * 64 + l];
        uint2 v2 = Tv[(size_t)s2 * 64 + l];
        uint2 v3 = Tv[(size_t)s3 * 64 + l];
        a0 += us2f(v0.x & 0xffffu); a1 += hi2f(v0.x); a2 += us2f(v0.y & 0xffffu); a3 += hi2f(v0.y);
        a0 += us2f(v1.x & 0xffffu); a1 += hi2f(v1.x); a2 += us2f(v1.y & 0xffffu); a3 += hi2f(v1.y);
        a0 += us2f(v2.x & 0xffffu); a1 += hi2f(v2.x); a2 += us2f(v2.y & 0xffffu); a3 += hi2f(v2.y);
        a0 += us2f(v3.x & 0xffffu); a1 += hi2f(v3.x); a2 += us2f(v3.y & 0xffffu); a3 += hi2f(v3.y);
    }
    for (; e < end; ++e) {
        int s = csr_src[e];
        uint2 v = Tv[(size_t)s * 64 + l];
        a0 += us2f(v.x & 0xffffu); a1 += hi2f(v.x); a2 += us2f(v.y & 0xffffu); a3 += hi2f(v.y);
    }
    {   // self-loop
        uint2 v = Tv[(size_t)n * 64 + l];
        a0 += us2f(v.x & 0xffffu); a1 += hi2f(v.x); a2 += us2f(v.y & 0xffffu); a3 += hi2f(v.y);
    }
    const float dv = dinv[n];
    uint2 o;
    o.x = pack2(a0 * dv, a1 * dv);
    o.y = pack2(a2 * dv, a3 * dv);
    if (l < 32) ((uint2*)OA)[(size_t)n * 32 + l] = o;
    else        ((uint2*)OB)[(size_t)n * 32 + (l - 32)] = o;
}

// ---------------- MFMA GEMM: T = X @ W + b (bf16 in via LDS; out bf16 or f32) ----------------
#define OM_F32 0
#define OM_BF16 1
#define OM_BF16_SR 2
template <int OMODE, int OSTRIDE>
__global__ __launch_bounds__(256) void gemm_mfma(const unsigned short* __restrict__ Xb,
                                                 const unsigned short* __restrict__ WT,
                                                 const float* __restrict__ bias,
                                                 const float* __restrict__ dinv,
                                                 void* __restrict__ T, int N) {
    __shared__ unsigned short Xs[64 * 128];   // 16 KB
    __shared__ unsigned short Ws[128 * 128];  // 32 KB
    const int tid = threadIdx.x;
    const int nb = blockIdx.x * 64;

    for (int c = tid; c < 2048; c += 256) {
        int n = c >> 4, kc = c & 15;
        ((uint4*)Ws)[(n << 4) | (kc ^ (n & 7))] = ((const uint4*)WT)[c];
    }
    for (int c = tid; c < 1024; c += 256) {
        int nl = c >> 4, kc = c & 15;
        int n = nb + nl;
        uint4 v = make_uint4(0u, 0u, 0u, 0u);
        if (n < N) v = ((const uint4*)(Xb + (size_t)n * HIDF))[kc];
        ((uint4*)Xs)[(nl << 4) | (kc ^ (nl & 7))] = v;
    }
    __syncthreads();

    const int wv   = tid >> 6;
    const int l    = tid & 63;
    const int row  = l & 15;
    const int kgrp = l >> 4;

    bf16x8 afr[4];
    #pragma unroll
    for (int kk = 0; kk < 4; ++kk) {
        int nl = 16 * wv + row;
        int kc = kk * 4 + kgrp;
        afr[kk] = *(const bf16x8*)(Xs + nl * 128 + ((kc ^ (nl & 7)) << 3));
    }

    f32x4 acc[8];
    #pragma unroll
    for (int nt = 0; nt < 8; ++nt) {
        float b = bias[nt * 16 + row];
        acc[nt] = (f32x4){b, b, b, b};
    }

    #pragma unroll
    for (int nt = 0; nt < 8; ++nt) {
        int col = nt * 16 + row;
        #pragma unroll
        for (int kk = 0; kk < 4; ++kk) {
            int kc = kk * 4 + kgrp;
            bf16x8 bfr = *(const bf16x8*)(Ws + col * 128 + ((kc ^ (col & 7)) << 3));
            acc[nt] = __builtin_amdgcn_mfma_f32_16x16x32_bf16(afr[kk], bfr, acc[nt], 0, 0, 0);
        }
    }

    float dv[4];
    if (OMODE == OM_BF16_SR) {
        #pragma unroll
        for (int r = 0; r < 4; ++r) {
            int grow = nb + 16 * wv + kgrp * 4 + r;
            dv[r] = (grow < N) ? dinv[grow] : 0.f;
        }
    }
    #pragma unroll
    for (int nt = 0; nt < 8; ++nt) {
        int gcol = nt * 16 + row;
        #pragma unroll
        for (int r = 0; r < 4; ++r) {
            int grow = nb + 16 * wv + kgrp * 4 + r;
            if (grow < N) {
                float v = acc[nt][r];
                if (OMODE == OM_BF16_SR) v = fmaxf(v, 0.f) * dv[r];
                if (OMODE == OM_F32) {
                    ((float*)T)[(size_t)grow * OSTRIDE + gcol] = v;
                } else {
                    ((unsigned short*)T)[(size_t)grow * OSTRIDE + gcol] = f2us(v);
                }
            }
        }
    }
}

// ---------------- meta: lane owns cols {2l, 2l+1}; vectorized loads ----------------
__global__ __launch_bounds__(256) void meta_kernel(const float* __restrict__ H1,
                                                   const unsigned* __restrict__ H2B,
                                                   const unsigned* __restrict__ H3B,
                                                   const float* __restrict__ Wa,
                                                   const float* __restrict__ ba,
                                                   const float* __restrict__ Wf,
                                                   const float* __restrict__ bfb,
                                                   float* __restrict__ out, int N) {
    __shared__ float WfS[HIDF * OUTF];  // 32 KB
    __shared__ float WaS[HIDF];
    __shared__ float hm[4][HIDF];
    const int tid = threadIdx.x;
    for (int i = tid; i < HIDF * OUTF; i += 256) WfS[i] = Wf[i];
    if (tid < HIDF) WaS[tid] = Wa[tid];
    __syncthreads();
    const float bav = ba[0];
    const int w = tid >> 6;
    const int l = tid & 63;
    const float bfv = bfb[l];
    const int iters = (N + 3) >> 2;

    for (int it = blockIdx.x; it < iters; it += gridDim.x) {
        const int n = it * 4 + w;
        __syncthreads();
        if (n < N) {
            float2   p1 = ((const float2*)(H1 + (size_t)n * HIDF))[l];
            unsigned u2 = H2B[(size_t)n * 64 + l];
            unsigned u3 = H3B[(size_t)n * 64 + l];
            float h1a = fmaxf(p1.x, 0.f),               h1b = fmaxf(p1.y, 0.f);
            float h2a = fmaxf(us2f(u2 & 0xffffu), 0.f), h2b = fmaxf(hi2f(u2), 0.f);
            float h3a = fmaxf(us2f(u3 & 0xffffu), 0.f), h3b = fmaxf(hi2f(u3), 0.f);
            float wa0 = WaS[2 * l], wa1 = WaS[2 * l + 1];
            float s1 = h1a * wa0 + h1b * wa1;
            float s2 = h2a * wa0 + h2b * wa1;
            float s3 = h3a * wa0 + h3b * wa1;
            #pragma unroll
            for (int off = 32; off; off >>= 1) {
                s1 += __shfl_xor(s1, off);
                s2 += __shfl_xor(s2, off);
                s3 += __shfl_xor(s3, off);
            }
            s1 += bav; s2 += bav; s3 += bav;
            float m  = fmaxf(s1, fmaxf(s2, s3));
            float e1 = expf(s1 - m), e2 = expf(s2 - m), e3 = expf(s3 - m);
            float inv = 1.f / (e1 + e2 + e3);
            float w1 = e1 * inv, w2 = e2 * inv, w3 = e3 * inv;
            hm[w][2 * l]     = w1 * h1a + w2 * h2a + w3 * h3a + h1a;
            hm[w][2 * l + 1] = w1 * h1b + w2 * h2b + w3 * h3b + h1b;
        }
        __syncthreads();
        if (n < N) {
            float acc = bfv;
            #pragma unroll
            for (int k = 0; k < HIDF; ++k) acc = fmaf(hm[w][k], WfS[k * OUTF + l], acc);
            out[(size_t)n * OUTF + l] = acc;
        }
    }
}

// ---------------- launch ----------------
extern "C" void kernel_launch(void* const* d_in, const int* in_sizes, int n_in,
                              void* d_out, int out_size, void* d_ws, size_t ws_size,
                              hipStream_t stream) {
    const float* x   = (const float*)d_in[0];
    const int*   ei  = (const int*)d_in[1];
    const float *W1  = (const float*)d_in[2],  *b1  = (const float*)d_in[3];
    const float *W21 = (const float*)d_in[4],  *b21 = (const float*)d_in[5];
    const float *W22 = (const float*)d_in[6],  *b22 = (const float*)d_in[7];
    const float *W31 = (const float*)d_in[8],  *b31 = (const float*)d_in[9];
    const float *W32 = (const float*)d_in[10], *b32 = (const float*)d_in[11];
    const float *W33 = (const float*)d_in[12], *b33 = (const float*)d_in[13];
    const float *Wa  = (const float*)d_in[14], *ba  = (const float*)d_in[15];
    const float *Wf  = (const float*)d_in[16], *bfb = (const float*)d_in[17];

    const int N = in_sizes[0] / HIDF;
    const int E = in_sizes[1] / 2;
    const int NBK = (N + 127) >> BK_SHIFT;

    int*      REND    = (int*)d_ws;                        // N  (row ends)
    int*      CSR_SRC = REND + N;                          // E
    unsigned* EDG     = (unsigned*)(CSR_SRC + E);          // E packed records
    int*      BCUR    = (int*)(EDG + E);                   // 1024*64 (padded)
    int*      BSIZE   = BCUR + 1024 * 64;                  // 1024*16 (padded)
    int*      BSTART  = BSIZE + 1024 * 16;                 // 1025
    float*    DINV    = (float*)(BSTART + 1040);           // N
    unsigned short* TB23 = (unsigned short*)(DINV + N);    // N*256 bf16 (later: H1F f32 N*128)
    unsigned* PXB  = (unsigned*)(TB23 + (size_t)N * 256);  // N*64 uints
    unsigned* AGA  = PXB + (size_t)N * 64;                 // N*64 uints
    unsigned* AGB  = AGA + (size_t)N * 64;                 // N*64 uints
    unsigned* H2B  = AGB + (size_t)N * 64;                 // N*64 uints
    unsigned short* WTB = (unsigned short*)(H2B + (size_t)N * 64);  // 6*16384 bf16

    const int gE    = (E + 255) / 256;
    const int gCVT  = (N * 32 + 255) / 256;
    const int gAGG  = (N * 64 + 255) / 256;
    const int gGEMM = (N + 63) / 64;
    const int gMETA = 2048;

    bhist_zero<<<(NBK * 16 + 255) / 256, 256, 0, stream>>>(BSIZE, NBK * 16);
    bhist_count<<<gE, 256, 0, stream>>>(ei, BSIZE, E);
    bscan<<<1, 1024, 0, stream>>>(BSIZE, BSTART, BCUR, NBK, E);
    bucket_scatter<<<gE, 256, 0, stream>>>(ei, BCUR, EDG, E);
    csr_build<<<NBK, 256, 0, stream>>>(EDG, BSTART, REND, CSR_SRC, DINV, N);
    cvt_w<<<384, 256, 0, stream>>>(W21, W31, W22, W32, W33, W1, WTB);

    unsigned short* TBX = TB23;   // plain [n][128] bf16 view of TB23 region

    cvt_scale<<<gCVT, 256, 0, stream>>>(x, DINV, TBX, N);
    agg_b2<<<gAGG, 256, 0, stream>>>(TBX, DINV, CSR_SRC, REND, PXB, N);

    gemm_mfma<OM_BF16_SR, 256><<<gGEMM, 256, 0, stream>>>((unsigned short*)PXB, WTB,         b21, DINV, TB23,       N);
    gemm_mfma<OM_BF16_SR, 256><<<gGEMM, 256, 0, stream>>>((unsigned short*)PXB, WTB + 16384, b31, DINV, TB23 + 128, N);
    agg_dual2<<<gAGG, 256, 0, stream>>>(TB23, DINV, CSR_SRC, REND, AGA, AGB, N);

    gemm_mfma<OM_BF16, 128><<<gGEMM, 256, 0, stream>>>((unsigned short*)AGA, WTB + 2 * 16384, b22, DINV, H2B, N);
    gemm_mfma<OM_BF16_SR, 128><<<gGEMM, 256, 0, stream>>>((unsigned short*)AGB, WTB + 3 * 16384, b32, DINV, TBX, N);
    agg_b2<<<gAGG, 256, 0, stream>>>(TBX, DINV, CSR_SRC, REND, AGA, N);
    gemm_mfma<OM_BF16, 128><<<gGEMM, 256, 0, stream>>>((unsigned short*)AGA, WTB + 4 * 16384, b33, DINV, AGB, N);

    float* H1F = (float*)TB23;
    gemm_mfma<OM_F32, 128><<<gGEMM, 256, 0, stream>>>((unsigned short*)PXB, WTB + 5 * 16384, b1, DINV, H1F, N);

    meta_kernel<<<gMETA, 256, 0, stream>>>(H1F, H2B, AGB, Wa, ba, Wf, bfb,
                                           (float*)d_out, N);
}

// Round 15
// 720.982 us; speedup vs baseline: 1.0472x; 1.0299x over previous
//
#include <hip/hip_runtime.h>
#include <hip/hip_bf16.h>

#define HIDF 128
#define OUTF 64
#define SCAN_B 256   // blocks in hierarchical scan
#define BK_SHIFT 7   // 128 nodes per CSR bucket

typedef __attribute__((ext_vector_type(8))) short bf16x8;
typedef __attribute__((ext_vector_type(4))) float f32x4;

__device__ __forceinline__ float us2f(unsigned u_lo16) {
    return __uint_as_float(u_lo16 << 16);
}
__device__ __forceinline__ float hi2f(unsigned u) {
    return __uint_as_float(u & 0xffff0000u);
}
__device__ __forceinline__ unsigned short f2us(float f) {
    __hip_bfloat16 h = __float2bfloat16(f);
    return *reinterpret_cast<unsigned short*>(&h);
}
__device__ __forceinline__ unsigned pack2(float a, float b) {
    return (unsigned)f2us(a) | ((unsigned)f2us(b) << 16);
}

// ---------------- degree / scan ----------------
__global__ __launch_bounds__(256) void deg_zero(int* __restrict__ d, int N) {
    int i = blockIdx.x * 256 + threadIdx.x;
    if (i < N) d[i] = 0;
}

__global__ __launch_bounds__(256) void deg_count(const int* __restrict__ ei, int* __restrict__ d, int E) {
    int e = blockIdx.x * 256 + threadIdx.x;
    if (e < E) atomicAdd(&d[ei[E + e]], 1);
}

__global__ __launch_bounds__(256) void scanA(const int* __restrict__ degi, int* __restrict__ blocksum, int N) {
    __shared__ int red[256];
    const int b = blockIdx.x;
    const int chunk = (N + SCAN_B - 1) / SCAN_B;
    const int lo = b * chunk, hi = min(lo + chunk, N);
    int s = 0;
    for (int i = lo + threadIdx.x; i < hi; i += 256) s += degi[i];
    red[threadIdx.x] = s;
    __syncthreads();
    for (int off = 128; off; off >>= 1) {
        if (threadIdx.x < off) red[threadIdx.x] += red[threadIdx.x + off];
        __syncthreads();
    }
    if (threadIdx.x == 0) blocksum[b] = red[0];
}

__global__ __launch_bounds__(256) void scanB(const int* __restrict__ blocksum, int* __restrict__ blockoff) {
    __shared__ int ps[256];
    const int t = threadIdx.x;
    ps[t] = blocksum[t];
    __syncthreads();
    for (int off = 1; off < 256; off <<= 1) {
        int v = ps[t];
        int u = (t >= off) ? ps[t - off] : 0;
        __syncthreads();
        ps[t] = v + u;
        __syncthreads();
    }
    blockoff[t] = (t == 0) ? 0 : ps[t - 1];
}

__global__ __launch_bounds__(256) void scanC(const int* __restrict__ degi,
                                             const int* __restrict__ blockoff,
                                             int* __restrict__ cursor,
                                             float* __restrict__ dinv, int N) {
    __shared__ int ps[256];
    const int b = blockIdx.x;
    const int chunk = (N + SCAN_B - 1) / SCAN_B;
    const int lo = b * chunk, hi = min(lo + chunk, N);
    const int tchunk = (chunk + 255) / 256;
    const int tlo = lo + threadIdx.x * tchunk;
    const int thi = min(tlo + tchunk, hi);
    int s = 0;
    for (int i = tlo; i < thi; ++i) s += degi[i];
    ps[threadIdx.x] = s;
    __syncthreads();
    for (int off = 1; off < 256; off <<= 1) {
        int v = ps[threadIdx.x];
        int u = (threadIdx.x >= off) ? ps[threadIdx.x - off] : 0;
        __syncthreads();
        ps[threadIdx.x] = v + u;
        __syncthreads();
    }
    int base = blockoff[b] + ((threadIdx.x == 0) ? 0 : ps[threadIdx.x - 1]);
    for (int i = tlo; i < thi; ++i) {
        int d = degi[i];
        cursor[i] = base;
        base += d;
        dinv[i] = rsqrtf((float)d + 1.f);
    }
}

// ---------------- bucketed CSR scatter (packed 4B records) ----------------
__global__ __launch_bounds__(256) void bcur_init(const int* __restrict__ cursor,
                                                 int* __restrict__ bcur, int N, int NBK) {
    int b = blockIdx.x * 256 + threadIdx.x;
    if (b < NBK) bcur[b * 64] = cursor[b << BK_SHIFT];
}

// pass 1: scatter packed (src<<7 | dst&127) into bucket-grouped regions of EDG
__global__ __launch_bounds__(256) void bucket_scatter(const int* __restrict__ ei,
                                                      int* __restrict__ bcur,
                                                      unsigned* __restrict__ edg, int E) {
    int e = blockIdx.x * 256 + threadIdx.x;
    if (e >= E) return;
    int src = ei[e];
    int dst = ei[E + e];
    int pos = atomicAdd(&bcur[(dst >> BK_SHIFT) * 64], 1);
    edg[pos] = ((unsigned)src << BK_SHIFT) | (unsigned)(dst & ((1 << BK_SHIFT) - 1));
}

// pass 2: one block per bucket; reconstruct dst, place src at final CSR position
__global__ __launch_bounds__(256) void final_scatter_b(const unsigned* __restrict__ edg,
                                                       const int* __restrict__ bcur,  // bucket ends
                                                       int* __restrict__ cursor,
                                                       int* __restrict__ csr_src) {
    const int b = blockIdx.x;
    __shared__ int sstart;
    if (threadIdx.x == 0) sstart = cursor[b << BK_SHIFT];  // unmutated: only this block touches bucket b
    __syncthreads();
    const int bstart = sstart;
    const int bend   = bcur[b * 64];
    const int base   = b << BK_SHIFT;
    for (int p = bstart + threadIdx.x; p < bend; p += 256) {
        unsigned u = edg[p];
        int src = (int)(u >> BK_SHIFT);
        int dst = base | (int)(u & ((1u << BK_SHIFT) - 1));
        int pos = atomicAdd(&cursor[dst], 1);
        csr_src[pos] = src;
    }
}

// ---------------- convert: TB[n,:] = bf16( x[n,:] * dinv[n] ) ----------------
__global__ __launch_bounds__(256) void cvt_scale(const float* __restrict__ X,
                                                 const float* __restrict__ dinv,
                                                 unsigned short* __restrict__ TB, int N) {
    int g = blockIdx.x * 256 + threadIdx.x;   // float4-group index
    if (g >= N * 32) return;
    int n = g >> 5;
    float dv = dinv[n];
    float4 v = ((const float4*)X)[g];
    ushort4 o;
    o.x = f2us(v.x * dv); o.y = f2us(v.y * dv);
    o.z = f2us(v.z * dv); o.w = f2us(v.w * dv);
    ((ushort4*)TB)[g] = o;
}

// ---------------- convert 6 weight matrices f32 [k][n] -> bf16 transposed [n][k] ----------------
__global__ __launch_bounds__(256) void cvt_w(const float* __restrict__ Wa0,
                                             const float* __restrict__ Wa1,
                                             const float* __restrict__ Wa2,
                                             const float* __restrict__ Wa3,
                                             const float* __restrict__ Wa4,
                                             const float* __restrict__ Wa5,
                                             unsigned short* __restrict__ WTB) {
    int t = blockIdx.x * 256 + threadIdx.x;
    if (t >= 6 * 16384) return;
    int m = t >> 14, local = t & 16383;
    int n = local >> 7, k = local & 127;
    const float* src = (m == 0) ? Wa0 : (m == 1) ? Wa1 : (m == 2) ? Wa2
                     : (m == 3) ? Wa3 : (m == 4) ? Wa4 : Wa5;
    WTB[t] = f2us(src[k * 128 + n]);
}

// ---------------- single CSR aggregation, paired-edge uint2 gather ----------------
// O[n,:] = bf16( dinv[n] * ( sum_src TB[src,:] + TB[n,:] ) ); rows pre-scaled by dinv[src].
// Wave halves process even/odd edges; lane owns an 8B (4-bf16) slot; shfl-combine at end.
__global__ __launch_bounds__(256) void agg_b2(const unsigned short* __restrict__ TB,
                                              const float* __restrict__ dinv,
                                              const int* __restrict__ csr_src,
                                              const int* __restrict__ rend,
                                              unsigned* __restrict__ O, int N) {
    const int n = (blockIdx.x * 256 + threadIdx.x) >> 6;
    const int l = threadIdx.x & 63;
    if (n >= N) return;
    const int half = l >> 5;
    const int sl   = l & 31;
    const int start = (n == 0) ? 0 : rend[n - 1];
    const int end   = rend[n];
    const uint2* Tv = (const uint2*)TB;   // row = 32 uint2 (256 B)

    float a0 = 0.f, a1 = 0.f, a2 = 0.f, a3 = 0.f;
    int e = start;
    for (; e + 8 <= end; e += 8) {        // 4 loads/lane in flight
        int sA = csr_src[e + 0 + half];
        int sB = csr_src[e + 2 + half];
        int sC = csr_src[e + 4 + half];
        int sD = csr_src[e + 6 + half];
        uint2 vA = Tv[(size_t)sA * 32 + sl];
        uint2 vB = Tv[(size_t)sB * 32 + sl];
        uint2 vC = Tv[(size_t)sC * 32 + sl];
        uint2 vD = Tv[(size_t)sD * 32 + sl];
        a0 += us2f(vA.x & 0xffffu); a1 += hi2f(vA.x); a2 += us2f(vA.y & 0xffffu); a3 += hi2f(vA.y);
        a0 += us2f(vB.x & 0xffffu); a1 += hi2f(vB.x); a2 += us2f(vB.y & 0xffffu); a3 += hi2f(vB.y);
        a0 += us2f(vC.x & 0xffffu); a1 += hi2f(vC.x); a2 += us2f(vC.y & 0xffffu); a3 += hi2f(vC.y);
        a0 += us2f(vD.x & 0xffffu); a1 += hi2f(vD.x); a2 += us2f(vD.y & 0xffffu); a3 += hi2f(vD.y);
    }
    for (; e + 2 <= end; e += 2) {
        int s = csr_src[e + half];
        uint2 v = Tv[(size_t)s * 32 + sl];
        a0 += us2f(v.x & 0xffffu); a1 += hi2f(v.x); a2 += us2f(v.y & 0xffffu); a3 += hi2f(v.y);
    }
    if (e < end && half == 0) {           // odd leftover edge
        int s = csr_src[e];
        uint2 v = Tv[(size_t)s * 32 + sl];
        a0 += us2f(v.x & 0xffffu); a1 += hi2f(v.x); a2 += us2f(v.y & 0xffffu); a3 += hi2f(v.y);
    }
    if (half == 0) {                      // self-loop
        uint2 v = Tv[(size_t)n * 32 + sl];
        a0 += us2f(v.x & 0xffffu); a1 += hi2f(v.x); a2 += us2f(v.y & 0xffffu); a3 += hi2f(v.y);
    }
    a0 += __shfl_xor(a0, 32); a1 += __shfl_xor(a1, 32);
    a2 += __shfl_xor(a2, 32); a3 += __shfl_xor(a3, 32);
    if (half == 0) {
        const float dv = dinv[n];
        uint2 o;
        o.x = pack2(a0 * dv, a1 * dv);
        o.y = pack2(a2 * dv, a3 * dv);
        ((uint2*)O)[(size_t)n * 32 + sl] = o;
    }
}

// ---------------- dual CSR aggregation: one 512B contiguous load covers both rows ----------------
__global__ __launch_bounds__(256) void agg_dual2(const unsigned short* __restrict__ TB23,
                                                 const float* __restrict__ dinv,
                                                 const int* __restrict__ csr_src,
                                                 const int* __restrict__ rend,
                                                 unsigned* __restrict__ OA,
                                                 unsigned* __restrict__ OB, int N) {
    const int n = (blockIdx.x * 256 + threadIdx.x) >> 6;
    const int l = threadIdx.x & 63;
    if (n >= N) return;
    const int start = (n == 0) ? 0 : rend[n - 1];
    const int end   = rend[n];
    const uint2* Tv = (const uint2*)TB23;  // node chunk = 64 uint2: slots 0-31 g2, 32-63 g3

    float a0 = 0.f, a1 = 0.f, a2 = 0.f, a3 = 0.f;
    int e = start;
    for (; e + 4 <= end; e += 4) {
        int s0 = csr_src[e + 0], s1 = csr_src[e + 1], s2 = csr_src[e + 2], s3 = csr_src[e + 3];
        uint2 v0 = Tv[(size_t)s0 * 64 + l];
        uint2 v1 = Tv[(size_t)s1 * 64 + l];
        uint2 v2 = Tv[(size_t)s2 * 64 + l];
        uint2 v3 = Tv[(size_t)s3 * 64 + l];
        a0 += us2f(v0.x & 0xffffu); a1 += hi2f(v0.x); a2 += us2f(v0.y & 0xffffu); a3 += hi2f(v0.y);
        a0 += us2f(v1.x & 0xffffu); a1 += hi2f(v1.x); a2 += us2f(v1.y & 0xffffu); a3 += hi2f(v1.y);
        a0 += us2f(v2.x & 0xffffu); a1 += hi2f(v2.x); a2 += us2f(v2.y & 0xffffu); a3 += hi2f(v2.y);
        a0 += us2f(v3.x & 0xffffu); a1 += hi2f(v3.x); a2 += us2f(v3.y & 0xffffu); a3 += hi2f(v3.y);
    }
    for (; e < end; ++e) {
        int s = csr_src[e];
        uint2 v = Tv[(size_t)s * 64 + l];
        a0 += us2f(v.x & 0xffffu); a1 += hi2f(v.x); a2 += us2f(v.y & 0xffffu); a3 += hi2f(v.y);
    }
    {   // self-loop
        uint2 v = Tv[(size_t)n * 64 + l];
        a0 += us2f(v.x & 0xffffu); a1 += hi2f(v.x); a2 += us2f(v.y & 0xffffu); a3 += hi2f(v.y);
    }
    const float dv = dinv[n];
    uint2 o;
    o.x = pack2(a0 * dv, a1 * dv);
    o.y = pack2(a2 * dv, a3 * dv);
    if (l < 32) ((uint2*)OA)[(size_t)n * 32 + l] = o;
    else        ((uint2*)OB)[(size_t)n * 32 + (l - 32)] = o;
}

// ---------------- MFMA GEMM: T = X @ W + b (bf16 in via LDS; out bf16 or f32) ----------------
#define OM_F32 0
#define OM_BF16 1
#define OM_BF16_SR 2
template <int OMODE, int OSTRIDE>
__global__ __launch_bounds__(256) void gemm_mfma(const unsigned short* __restrict__ Xb,
                                                 const unsigned short* __restrict__ WT,  // [n][k] bf16
                                                 const float* __restrict__ bias,
                                                 const float* __restrict__ dinv,
                                                 void* __restrict__ T, int N) {
    __shared__ unsigned short Xs[64 * 128];   // 16 KB
    __shared__ unsigned short Ws[128 * 128];  // 32 KB
    const int tid = threadIdx.x;
    const int nb = blockIdx.x * 64;

    for (int c = tid; c < 2048; c += 256) {
        int n = c >> 4, kc = c & 15;
        ((uint4*)Ws)[(n << 4) | (kc ^ (n & 7))] = ((const uint4*)WT)[c];
    }
    for (int c = tid; c < 1024; c += 256) {
        int nl = c >> 4, kc = c & 15;
        int n = nb + nl;
        uint4 v = make_uint4(0u, 0u, 0u, 0u);
        if (n < N) v = ((const uint4*)(Xb + (size_t)n * HIDF))[kc];
        ((uint4*)Xs)[(nl << 4) | (kc ^ (nl & 7))] = v;
    }
    __syncthreads();

    const int wv   = tid >> 6;
    const int l    = tid & 63;
    const int row  = l & 15;
    const int kgrp = l >> 4;

    bf16x8 afr[4];
    #pragma unroll
    for (int kk = 0; kk < 4; ++kk) {
        int nl = 16 * wv + row;
        int kc = kk * 4 + kgrp;
        afr[kk] = *(const bf16x8*)(Xs + nl * 128 + ((kc ^ (nl & 7)) << 3));
    }

    f32x4 acc[8];
    #pragma unroll
    for (int nt = 0; nt < 8; ++nt) {
        float b = bias[nt * 16 + row];
        acc[nt] = (f32x4){b, b, b, b};
    }

    #pragma unroll
    for (int nt = 0; nt < 8; ++nt) {
        int col = nt * 16 + row;
        #pragma unroll
        for (int kk = 0; kk < 4; ++kk) {
            int kc = kk * 4 + kgrp;
            bf16x8 bfr = *(const bf16x8*)(Ws + col * 128 + ((kc ^ (col & 7)) << 3));
            acc[nt] = __builtin_amdgcn_mfma_f32_16x16x32_bf16(afr[kk], bfr, acc[nt], 0, 0, 0);
        }
    }

    float dv[4];
    if (OMODE == OM_BF16_SR) {
        #pragma unroll
        for (int r = 0; r < 4; ++r) {
            int grow = nb + 16 * wv + kgrp * 4 + r;
            dv[r] = (grow < N) ? dinv[grow] : 0.f;
        }
    }
    #pragma unroll
    for (int nt = 0; nt < 8; ++nt) {
        int gcol = nt * 16 + row;
        #pragma unroll
        for (int r = 0; r < 4; ++r) {
            int grow = nb + 16 * wv + kgrp * 4 + r;
            if (grow < N) {
                float v = acc[nt][r];
                if (OMODE == OM_BF16_SR) v = fmaxf(v, 0.f) * dv[r];
                if (OMODE == OM_F32) {
                    ((float*)T)[(size_t)grow * OSTRIDE + gcol] = v;
                } else {
                    ((unsigned short*)T)[(size_t)grow * OSTRIDE + gcol] = f2us(v);
                }
            }
        }
    }
}

// ---------------- meta: lane owns cols {2l, 2l+1}; vectorized loads ----------------
__global__ __launch_bounds__(256) void meta_kernel(const float* __restrict__ H1,
                                                   const unsigned* __restrict__ H2B,
                                                   const unsigned* __restrict__ H3B,
                                                   const float* __restrict__ Wa,
                                                   const float* __restrict__ ba,
                                                   const float* __restrict__ Wf,
                                                   const float* __restrict__ bfb,
                                                   float* __restrict__ out, int N) {
    __shared__ float WfS[HIDF * OUTF];  // 32 KB
    __shared__ float WaS[HIDF];
    __shared__ float hm[4][HIDF];
    const int tid = threadIdx.x;
    for (int i = tid; i < HIDF * OUTF; i += 256) WfS[i] = Wf[i];
    if (tid < HIDF) WaS[tid] = Wa[tid];
    __syncthreads();
    const float bav = ba[0];
    const int w = tid >> 6;
    const int l = tid & 63;
    const float bfv = bfb[l];
    const int iters = (N + 3) >> 2;

    for (int it = blockIdx.x; it < iters; it += gridDim.x) {
        const int n = it * 4 + w;
        __syncthreads();
        if (n < N) {
            float2   p1 = ((const float2*)(H1 + (size_t)n * HIDF))[l];     // cols 2l,2l+1
            unsigned u2 = H2B[(size_t)n * 64 + l];
            unsigned u3 = H3B[(size_t)n * 64 + l];
            float h1a = fmaxf(p1.x, 0.f),               h1b = fmaxf(p1.y, 0.f);
            float h2a = fmaxf(us2f(u2 & 0xffffu), 0.f), h2b = fmaxf(hi2f(u2), 0.f);
            float h3a = fmaxf(us2f(u3 & 0xffffu), 0.f), h3b = fmaxf(hi2f(u3), 0.f);
            float wa0 = WaS[2 * l], wa1 = WaS[2 * l + 1];
            float s1 = h1a * wa0 + h1b * wa1;
            float s2 = h2a * wa0 + h2b * wa1;
            float s3 = h3a * wa0 + h3b * wa1;
            #pragma unroll
            for (int off = 32; off; off >>= 1) {
                s1 += __shfl_xor(s1, off);
                s2 += __shfl_xor(s2, off);
                s3 += __shfl_xor(s3, off);
            }
            s1 += bav; s2 += bav; s3 += bav;
            float m  = fmaxf(s1, fmaxf(s2, s3));
            float e1 = expf(s1 - m), e2 = expf(s2 - m), e3 = expf(s3 - m);
            float inv = 1.f / (e1 + e2 + e3);
            float w1 = e1 * inv, w2 = e2 * inv, w3 = e3 * inv;
            hm[w][2 * l]     = w1 * h1a + w2 * h2a + w3 * h3a + h1a;
            hm[w][2 * l + 1] = w1 * h1b + w2 * h2b + w3 * h3b + h1b;
        }
        __syncthreads();
        if (n < N) {
            float acc = bfv;
            #pragma unroll
            for (int k = 0; k < HIDF; ++k) acc = fmaf(hm[w][k], WfS[k * OUTF + l], acc);
            out[(size_t)n * OUTF + l] = acc;
        }
    }
}

// ---------------- launch ----------------
extern "C" void kernel_launch(void* const* d_in, const int* in_sizes, int n_in,
                              void* d_out, int out_size, void* d_ws, size_t ws_size,
                              hipStream_t stream) {
    const float* x   = (const float*)d_in[0];
    const int*   ei  = (const int*)d_in[1];
    const float *W1  = (const float*)d_in[2],  *b1  = (const float*)d_in[3];
    const float *W21 = (const float*)d_in[4],  *b21 = (const float*)d_in[5];
    const float *W22 = (const float*)d_in[6],  *b22 = (const float*)d_in[7];
    const float *W31 = (const float*)d_in[8],  *b31 = (const float*)d_in[9];
    const float *W32 = (const float*)d_in[10], *b32 = (const float*)d_in[11];
    const float *W33 = (const float*)d_in[12], *b33 = (const float*)d_in[13];
    const float *Wa  = (const float*)d_in[14], *ba  = (const float*)d_in[15];
    const float *Wf  = (const float*)d_in[16], *bfb = (const float*)d_in[17];

    const int N = in_sizes[0] / HIDF;
    const int E = in_sizes[1] / 2;
    const int NBK = (N + 127) >> BK_SHIFT;

    // workspace: ints | DINV | TB23 (later aliased by H1F f32) | PXB | AGA | AGB | H2B | WTB
    int*      DEGI    = (int*)d_ws;                        // N
    int*      CURSOR  = DEGI + N;                          // N
    int*      CSR_SRC = CURSOR + N;                        // E
    unsigned* EDG     = (unsigned*)(CSR_SRC + E);          // E packed records
    int*      BCUR    = (int*)(EDG + E);                   // 1024*64 (padded)
    int*      BSUM    = BCUR + 1024 * 64;                  // 256
    int*      BOFF    = BSUM + 256;                        // 256
    float*    DINV    = (float*)(BOFF + 256);              // N
    unsigned short* TB23 = (unsigned short*)(DINV + N);    // N*256 bf16 (later: H1F f32 N*128)
    unsigned* PXB  = (unsigned*)(TB23 + (size_t)N * 256);  // N*64 uints (bf16 pairs)
    unsigned* AGA  = PXB + (size_t)N * 64;                 // N*64 uints
    unsigned* AGB  = AGA + (size_t)N * 64;                 // N*64 uints
    unsigned* H2B  = AGB + (size_t)N * 64;                 // N*64 uints
    unsigned short* WTB = (unsigned short*)(H2B + (size_t)N * 64);  // 6*16384 bf16

    const int gE    = (E + 255) / 256;
    const int gCVT  = (N * 32 + 255) / 256;
    const int gAGG  = (N * 64 + 255) / 256;
    const int gGEMM = (N + 63) / 64;
    const int gMETA = 2048;
    const int gN    = (N + 255) / 256;

    // CSR build (r12 pipeline) + weight pre-transpose
    deg_zero<<<gN, 256, 0, stream>>>(DEGI, N);
    deg_count<<<gE, 256, 0, stream>>>(ei, DEGI, E);
    scanA<<<SCAN_B, 256, 0, stream>>>(DEGI, BSUM, N);
    scanB<<<1, 256, 0, stream>>>(BSUM, BOFF);
    scanC<<<SCAN_B, 256, 0, stream>>>(DEGI, BOFF, CURSOR, DINV, N);
    bcur_init<<<(NBK + 255) / 256, 256, 0, stream>>>(CURSOR, BCUR, N, NBK);
    bucket_scatter<<<gE, 256, 0, stream>>>(ei, BCUR, EDG, E);
    final_scatter_b<<<NBK, 256, 0, stream>>>(EDG, BCUR, CURSOR, CSR_SRC);
    cvt_w<<<384, 256, 0, stream>>>(W21, W31, W22, W32, W33, W1, WTB);

    unsigned short* TBX = TB23;   // plain [n][128] bf16 view of TB23 region

    // TBX = bf16(x*dinv); PXB = bf16( P x )
    cvt_scale<<<gCVT, 256, 0, stream>>>(x, DINV, TBX, N);
    agg_b2<<<gAGG, 256, 0, stream>>>(TBX, DINV, CSR_SRC, CURSOR, PXB, N);

    // branch layer-1: TB23 = {g2, g3}
    gemm_mfma<OM_BF16_SR, 256><<<gGEMM, 256, 0, stream>>>((unsigned short*)PXB, WTB,         b21, DINV, TB23,       N);
    gemm_mfma<OM_BF16_SR, 256><<<gGEMM, 256, 0, stream>>>((unsigned short*)PXB, WTB + 16384, b31, DINV, TB23 + 128, N);
    // fused aggregation: AGA = P g2, AGB = P g3
    agg_dual2<<<gAGG, 256, 0, stream>>>(TB23, DINV, CSR_SRC, CURSOR, AGA, AGB, N);

    // h2 finish: H2B = AGA@W22+b22
    gemm_mfma<OM_BF16, 128><<<gGEMM, 256, 0, stream>>>((unsigned short*)AGA, WTB + 2 * 16384, b22, DINV, H2B, N);
    // h3 second layer: TBX = relu(AGB@W32+b32)*dinv
    gemm_mfma<OM_BF16_SR, 128><<<gGEMM, 256, 0, stream>>>((unsigned short*)AGB, WTB + 3 * 16384, b32, DINV, TBX, N);
    // h3 aggregation: AGA = P TBX
    agg_b2<<<gAGG, 256, 0, stream>>>(TBX, DINV, CSR_SRC, CURSOR, AGA, N);
    // h3 finish: H3B (=AGB) = AGA@W33+b33
    gemm_mfma<OM_BF16, 128><<<gGEMM, 256, 0, stream>>>((unsigned short*)AGA, WTB + 4 * 16384, b33, DINV, AGB, N);

    // h1: H1F (f32, aliases TB23 region; TBX dead) = PXB@W1+b1
    float* H1F = (float*)TB23;
    gemm_mfma<OM_F32, 128><<<gGEMM, 256, 0, stream>>>((unsigned short*)PXB, WTB + 5 * 16384, b1, DINV, H1F, N);

    // meta combine + final projection
    meta_kernel<<<gMETA, 256, 0, stream>>>(H1F, H2B, AGB, Wa, ba, Wf, bfb,
                                           (float*)d_out, N);
}